// Round 8
// baseline (698.199 us; speedup 1.0000x reference)
//
#include <hip/hip_runtime.h>
#include <hip/hip_fp16.h>

#define N_NODES 100000
#define N_EDGES 1600000
#define HDIM 64
#define NPB 512                                  // nodes per bucket (pow2)
#define NPB_SHIFT 9
#define NBUCK 196                                // ceil(100000/512)
#define CAP 16384                                // per-bucket slot capacity
#define NCHUNK 256                               // place blocks (R4-measured config)
#define CHUNK (N_EDGES / NCHUNK)                 // 6250 edges/block
#define GBLK 3125                                // gather blocks (32 rows, N = 3125*32)

typedef float f4v __attribute__((ext_vector_type(4)));

// ---------------- K0: init global bucket cursors ----------------
__global__ void init_kernel(int* __restrict__ gcurD, int* __restrict__ gcurS) {
    int t = threadIdx.x;
    if (t < NBUCK) {
        gcurD[t] = t * CAP;
        gcurS[t] = t * CAP;
    }
}

__device__ inline uint2 f4_to_h4(float x, float y, float z, float w) {
    __half2 lo = __floats2half2_rn(x, y);
    __half2 hi = __floats2half2_rn(z, w);
    uint2 r;
    r.x = *(unsigned*)&lo;
    r.y = *(unsigned*)&hi;
    return r;
}

// ---------------- K1: place edges into fixed-capacity bucket regions (EXACT R4) ----------------
// LDS-cursor run reservation; NO global scattered atomics (R7: 75us disaster).
// bufD entry: src | (local_dst << 17)
__global__ void place_kernel(const int* __restrict__ src, const int* __restrict__ dst,
                             int* __restrict__ gcurD, int* __restrict__ gcurS,
                             unsigned int* __restrict__ bufD, unsigned short* __restrict__ bufS) {
    __shared__ int hD[NBUCK], hS[NBUCK], curD[NBUCK], curS[NBUCK];
    int t = threadIdx.x, blk = blockIdx.x;
    for (int i = t; i < NBUCK; i += 256) { hD[i] = 0; hS[i] = 0; }
    __syncthreads();
    int e0 = blk * CHUNK;
    // pass 1: count (chunk ~50 KB -> L1/L2 hot for pass 2)
    for (int i = t; i < CHUNK; i += 256) {
        atomicAdd(&hD[dst[e0 + i] >> NPB_SHIFT], 1);
        atomicAdd(&hS[src[e0 + i] >> NPB_SHIFT], 1);
    }
    __syncthreads();
    // reserve runs
    for (int i = t; i < NBUCK; i += 256) {
        curD[i] = hD[i] ? atomicAdd(&gcurD[i], hD[i]) : 0;
        curS[i] = hS[i] ? atomicAdd(&gcurS[i], hS[i]) : 0;
    }
    __syncthreads();
    // pass 2: scatter
    for (int i = t; i < CHUNK; i += 256) {
        int s = src[e0 + i], d = dst[e0 + i];
        int pd = atomicAdd(&curD[d >> NPB_SHIFT], 1);
        bufD[pd] = (unsigned)s | ((unsigned)(d & (NPB - 1)) << 17);
        int ps = atomicAdd(&curS[s >> NPB_SHIFT], 1);
        bufS[ps] = (unsigned short)(s & (NPB - 1));
    }
}

// ---------------- K2: dst-bucket sort ∥ (src-bucket count + dense-1 fused) ----------------
// blocks [0,196): dst buckets -> csr_src, offs, inv_in (wave-shfl scan, R7-verified)
// blocks [196,392): src bucket b: count bufS -> LDS inv scales -> write inv_out ->
//                   dense-1 for OWN 512 rows: hw[row] = (inv*features[row]) @ W.
// Self-contained per block: no cross-block race on inv_out (each block computes what
// it consumes). Dense rides in the shadow of the concurrently-running dst blocks.
// LDS sum ~22 KB @512thr -> 4 blocks/CU = thread cap anyway.
__global__ void bucket_dense_kernel(const unsigned int* __restrict__ bufD,
                                    const unsigned short* __restrict__ bufS,
                                    const int* __restrict__ gcurD, const int* __restrict__ gcurS,
                                    int* __restrict__ csr_src, int2* __restrict__ offs,
                                    float* __restrict__ inv_in, float* __restrict__ inv_out,
                                    const float* __restrict__ h, const float* __restrict__ W,
                                    uint2* __restrict__ hw, int n) {
    int t = threadIdx.x;   // blockDim = 512
    int blk = blockIdx.x;
    if (blk < NBUCK) {
        // ---- dst bucket: counting sort ----
        __shared__ int cnt[NPB], cur[NPB];
        __shared__ int wsum[8];
        int b = blk;
        int ebase = b * CAP;
        int ecnt  = gcurD[b] - ebase;
        cnt[t] = 0;
        __syncthreads();
        for (int i = t; i < ecnt; i += NPB)
            atomicAdd(&cnt[(int)(bufD[ebase + i] >> 17)], 1);
        __syncthreads();
        int v = cnt[t];
        // wave-level inclusive scan (6 shfl steps) + 8-wave LDS combine (R7-verified)
        int lane = t & 63, w = t >> 6;
        int p = v;
#pragma unroll
        for (int d = 1; d < 64; d <<= 1) {
            int x = __shfl_up(p, d, 64);
            if (lane >= d) p += x;
        }
        if (lane == 63) wsum[w] = p;
        __syncthreads();
        int base = 0;
#pragma unroll
        for (int i = 0; i < 8; ++i) base += (i < w) ? wsum[i] : 0;
        int excl = base + p - v;
        cur[t] = excl;
        int node = b * NPB + t;
        if (node < N_NODES) {
            offs[node] = make_int2(ebase + excl, ebase + excl + v);
            inv_in[node] = rsqrtf((float)max(v, 1));
        }
        __syncthreads();
        for (int i = t; i < ecnt; i += NPB) {
            unsigned en = bufD[ebase + i];
            int pos = atomicAdd(&cur[(int)(en >> 17)], 1);
            csr_src[ebase + pos] = (int)(en & 0x1FFFFu);
        }
    } else {
        // ---- src bucket: count -> inv scales -> fused dense-1 for own 512 rows ----
        __shared__ int scnt[NPB];
        __shared__ float sinv[NPB];
        __shared__ float Wlds[HDIM * HDIM];     // 16 KB
        int b = blk - NBUCK;
        int ebase = b * CAP;
        int ecnt  = gcurS[b] - ebase;
        for (int i = t; i < HDIM * HDIM / 4; i += 512)
            ((f4v*)Wlds)[i] = ((const f4v*)W)[i];
        scnt[t] = 0;
        __syncthreads();
        for (int i = t; i < ecnt; i += NPB)
            atomicAdd(&scnt[(int)bufS[ebase + i]], 1);
        __syncthreads();
        float inv = rsqrtf((float)max(scnt[t], 1));
        int node = b * NPB + t;
        if (node < n) inv_out[node] = inv;     // still needed by gather_dense epilogue
        sinv[t] = inv;
        __syncthreads();

        // dense-1 (shfl form, R7-verified): 8 passes x 64 rows; lane gl owns cols [8gl,8gl+8)
        int rr = t >> 3, gl = t & 7;
        int gbase = (t & 63) & 56;              // 8-lane group base within wave
        for (int pss = 0; pss < 8; ++pss) {
            int r = pss * 64 + rr;              // row-in-bucket 0..511
            int row = b * NPB + r;
            f4v a0 = {0.f, 0.f, 0.f, 0.f}, a1 = a0;
            if (row < n) {
                float so = sinv[r];
                a0 = __builtin_nontemporal_load((const f4v*)h + (long long)row * 16 + gl * 2 + 0);
                a1 = __builtin_nontemporal_load((const f4v*)h + (long long)row * 16 + gl * 2 + 1);
                a0.x *= so; a0.y *= so; a0.z *= so; a0.w *= so;
                a1.x *= so; a1.y *= so; a1.z *= so; a1.w *= so;
            }
            float acc0 = 0.f, acc1 = 0.f, acc2 = 0.f, acc3 = 0.f;
            float acc4 = 0.f, acc5 = 0.f, acc6 = 0.f, acc7 = 0.f;
#pragma unroll
            for (int k = 0; k < HDIM; ++k) {
                float av = ((k >> 2) & 1) ? a1[k & 3] : a0[k & 3];   // static component
                float ak = __shfl(av, gbase + (k >> 3), 64);
                f4v w0 = ((const f4v*)Wlds)[k * 16 + gl * 2 + 0];
                f4v w1 = ((const f4v*)Wlds)[k * 16 + gl * 2 + 1];
                acc0 = fmaf(ak, w0.x, acc0); acc1 = fmaf(ak, w0.y, acc1);
                acc2 = fmaf(ak, w0.z, acc2); acc3 = fmaf(ak, w0.w, acc3);
                acc4 = fmaf(ak, w1.x, acc4); acc5 = fmaf(ak, w1.y, acc5);
                acc6 = fmaf(ak, w1.z, acc6); acc7 = fmaf(ak, w1.w, acc7);
            }
            if (row < n) {
                hw[(long long)row * 16 + gl * 2 + 0] = f4_to_h4(acc0, acc1, acc2, acc3);
                hw[(long long)row * 16 + gl * 2 + 1] = f4_to_h4(acc4, acc5, acc6, acc7);
            }
        }
    }
}

// ---------------- K3: fused layer-1 gather + layer-2 dense (EXACT R4) ----------------
__global__ void gather_dense_kernel(const uint4* __restrict__ hw_in, const float* __restrict__ inv_in,
                                    const float* __restrict__ inv_out,
                                    const int2* __restrict__ offs, const int* __restrict__ csr_src,
                                    const float* __restrict__ bias, const float* __restrict__ W,
                                    uint2* __restrict__ hw_out, int n) {
    __shared__ float Wlds[HDIM * HDIM];     // 16 KB
    int t = threadIdx.x;
    for (int i = t; i < HDIM * HDIM / 4; i += 256)
        ((f4v*)Wlds)[i] = ((const f4v*)W)[i];

    int wave = t >> 6, lane = t & 63;
    int g = lane >> 3, gl = lane & 7;          // group 0..7, lane-in-group 0..7
    int row = blockIdx.x * 32 + wave * 8 + g;  // N = 3125 * 32 exactly -> always valid

    float acc0 = 0.f, acc1 = 0.f, acc2 = 0.f, acc3 = 0.f;
    float acc4 = 0.f, acc5 = 0.f, acc6 = 0.f, acc7 = 0.f;

    int2 oe = offs[row];
    int start = oe.x, end = oe.y;
    int gbase = g << 3;

    int jb = start;
    int mm = end - jb; if (mm > 8) mm = 8;
    int sidx = (mm > 0 && gl < mm) ? csr_src[jb + gl] : 0;

    while (jb < end) {
        int jb2 = jb + 8;
        int mm2 = end - jb2; if (mm2 > 8) mm2 = 8;
        int sidx2 = (jb2 < end && gl < mm2) ? csr_src[jb2 + gl] : 0;

        if (mm == 8) {
#pragma unroll
            for (int j = 0; j < 8; ++j) {
                int s = __shfl(sidx, gbase + j, 64);
                uint4 u = hw_in[(long long)s * 8 + gl];
                float2 f0 = __half22float2(*(__half2*)&u.x);
                float2 f1 = __half22float2(*(__half2*)&u.y);
                float2 f2 = __half22float2(*(__half2*)&u.z);
                float2 f3 = __half22float2(*(__half2*)&u.w);
                acc0 += f0.x; acc1 += f0.y; acc2 += f1.x; acc3 += f1.y;
                acc4 += f2.x; acc5 += f2.y; acc6 += f3.x; acc7 += f3.y;
            }
        } else {
            for (int j = 0; j < mm; ++j) {
                int s = __shfl(sidx, gbase + j, 64);
                uint4 u = hw_in[(long long)s * 8 + gl];
                float2 f0 = __half22float2(*(__half2*)&u.x);
                float2 f1 = __half22float2(*(__half2*)&u.y);
                float2 f2 = __half22float2(*(__half2*)&u.z);
                float2 f3 = __half22float2(*(__half2*)&u.w);
                acc0 += f0.x; acc1 += f0.y; acc2 += f1.x; acc3 += f1.y;
                acc4 += f2.x; acc5 += f2.y; acc6 += f3.x; acc7 += f3.y;
            }
        }
        jb = jb2; mm = mm2; sidx = sidx2;
    }

    // finish layer 1 in registers: h1 = relu(acc*inv_in + bias), pre-scale by inv_out[row]
    float sc = inv_in[row];
    float so = inv_out[row];                   // per-ROW scalar (not per-edge)
    float4 b0 = ((const float4*)bias)[gl * 2 + 0];
    float4 b1 = ((const float4*)bias)[gl * 2 + 1];
    f4v h0, h1;
    h0.x = fmaxf(fmaf(acc0, sc, b0.x), 0.f) * so;
    h0.y = fmaxf(fmaf(acc1, sc, b0.y), 0.f) * so;
    h0.z = fmaxf(fmaf(acc2, sc, b0.z), 0.f) * so;
    h0.w = fmaxf(fmaf(acc3, sc, b0.w), 0.f) * so;
    h1.x = fmaxf(fmaf(acc4, sc, b1.x), 0.f) * so;
    h1.y = fmaxf(fmaf(acc5, sc, b1.y), 0.f) * so;
    h1.z = fmaxf(fmaf(acc6, sc, b1.z), 0.f) * so;
    h1.w = fmaxf(fmaf(acc7, sc, b1.w), 0.f) * so;

    __syncthreads();   // Wlds ready (all lanes reach here: no early returns)

    // layer-2 dense: hw_out[row] = (so*h1row) @ W
    float d0 = 0.f, d1 = 0.f, d2 = 0.f, d3 = 0.f;
    float d4 = 0.f, d5 = 0.f, d6 = 0.f, d7 = 0.f;
#pragma unroll
    for (int k = 0; k < HDIM; ++k) {
        float av = ((k >> 2) & 1) ? h1[k & 3] : h0[k & 3];   // static component
        float ak = __shfl(av, gbase + (k >> 3), 64);
        f4v w0 = ((const f4v*)Wlds)[k * 16 + gl * 2 + 0];
        f4v w1 = ((const f4v*)Wlds)[k * 16 + gl * 2 + 1];
        d0 = fmaf(ak, w0.x, d0); d1 = fmaf(ak, w0.y, d1);
        d2 = fmaf(ak, w0.z, d2); d3 = fmaf(ak, w0.w, d3);
        d4 = fmaf(ak, w1.x, d4); d5 = fmaf(ak, w1.y, d5);
        d6 = fmaf(ak, w1.z, d6); d7 = fmaf(ak, w1.w, d7);
    }

    hw_out[(long long)row * 16 + gl * 2 + 0] = f4_to_h4(d0, d1, d2, d3);
    hw_out[(long long)row * 16 + gl * 2 + 1] = f4_to_h4(d4, d5, d6, d7);
}

// ---------------- K4: final gather (EXACT R4): out = relu(inv_in*sum + b) ----------------
__global__ void gather_kernel(const uint4* __restrict__ hw, const float* __restrict__ inv_in,
                              const int2* __restrict__ offs, const int* __restrict__ csr_src,
                              const float* __restrict__ bias, float* __restrict__ out, int n) {
    int t = threadIdx.x;
    int wave = t >> 6, lane = t & 63;
    int g = lane >> 3, gl = lane & 7;
    int row = blockIdx.x * 32 + wave * 8 + g;
    if (row >= n) return;

    float acc0 = 0.f, acc1 = 0.f, acc2 = 0.f, acc3 = 0.f;
    float acc4 = 0.f, acc5 = 0.f, acc6 = 0.f, acc7 = 0.f;

    int2 oe = offs[row];
    int jb = oe.x, end = oe.y;
    int gbase = g << 3;

    int mm = end - jb; if (mm > 8) mm = 8;
    int sidx = (mm > 0 && gl < mm) ? csr_src[jb + gl] : 0;

    while (jb < end) {
        int jb2 = jb + 8;
        int mm2 = end - jb2; if (mm2 > 8) mm2 = 8;
        int sidx2 = (jb2 < end && gl < mm2) ? csr_src[jb2 + gl] : 0;

        if (mm == 8) {
#pragma unroll
            for (int j = 0; j < 8; ++j) {
                int s = __shfl(sidx, gbase + j, 64);
                uint4 u = hw[(long long)s * 8 + gl];
                float2 f0 = __half22float2(*(__half2*)&u.x);
                float2 f1 = __half22float2(*(__half2*)&u.y);
                float2 f2 = __half22float2(*(__half2*)&u.z);
                float2 f3 = __half22float2(*(__half2*)&u.w);
                acc0 += f0.x; acc1 += f0.y; acc2 += f1.x; acc3 += f1.y;
                acc4 += f2.x; acc5 += f2.y; acc6 += f3.x; acc7 += f3.y;
            }
        } else {
            for (int j = 0; j < mm; ++j) {
                int s = __shfl(sidx, gbase + j, 64);
                uint4 u = hw[(long long)s * 8 + gl];
                float2 f0 = __half22float2(*(__half2*)&u.x);
                float2 f1 = __half22float2(*(__half2*)&u.y);
                float2 f2 = __half22float2(*(__half2*)&u.z);
                float2 f3 = __half22float2(*(__half2*)&u.w);
                acc0 += f0.x; acc1 += f0.y; acc2 += f1.x; acc3 += f1.y;
                acc4 += f2.x; acc5 += f2.y; acc6 += f3.x; acc7 += f3.y;
            }
        }
        jb = jb2; mm = mm2; sidx = sidx2;
    }

    float sc = inv_in[row];
    float4 b0 = ((const float4*)bias)[gl * 2 + 0];
    float4 b1 = ((const float4*)bias)[gl * 2 + 1];
    f4v r0, r1;
    r0.x = fmaxf(fmaf(acc0, sc, b0.x), 0.f);
    r0.y = fmaxf(fmaf(acc1, sc, b0.y), 0.f);
    r0.z = fmaxf(fmaf(acc2, sc, b0.z), 0.f);
    r0.w = fmaxf(fmaf(acc3, sc, b0.w), 0.f);
    r1.x = fmaxf(fmaf(acc4, sc, b1.x), 0.f);
    r1.y = fmaxf(fmaf(acc5, sc, b1.y), 0.f);
    r1.z = fmaxf(fmaf(acc6, sc, b1.z), 0.f);
    r1.w = fmaxf(fmaf(acc7, sc, b1.w), 0.f);
    __builtin_nontemporal_store(r0, (f4v*)out + (long long)row * 16 + gl * 2 + 0);
    __builtin_nontemporal_store(r1, (f4v*)out + (long long)row * 16 + gl * 2 + 1);
}

extern "C" void kernel_launch(void* const* d_in, const int* in_sizes, int n_in,
                              void* d_out, int out_size, void* d_ws, size_t ws_size,
                              hipStream_t stream) {
    const float* features = (const float*)d_in[0];   // [N, 64]
    const float* W        = (const float*)d_in[1];   // [64, 64]
    const float* b        = (const float*)d_in[2];   // [64]
    const int*   src      = (const int*)d_in[3];     // [E]
    const int*   dst      = (const int*)d_in[4];     // [E]

    float* out = (float*)d_out;                      // [N, 64]

    // workspace layout (4-byte words); ~59 MB of 256 MB ws (same as R4)
    float* ws = (float*)d_ws;
    uint2* hw  = (uint2*)ws;                                            // N*32 words
    uint2* hw2 = (uint2*)(ws + (size_t)N_NODES * 32);                   // N*32 words
    unsigned int*   bufD = (unsigned int*)(ws + (size_t)N_NODES * 64);  // NBUCK*CAP words
    unsigned short* bufS = (unsigned short*)(bufD + (size_t)NBUCK * CAP); // NBUCK*CAP u16
    int*   csr_src = (int*)(bufS + (size_t)NBUCK * CAP);                // NBUCK*CAP words
    int2*  offs    = (int2*)(csr_src + (size_t)NBUCK * CAP);            // N int2
    float* inv_out = (float*)(offs + N_NODES);       // N
    float* inv_in  = inv_out + N_NODES;              // N
    int*   gcurD   = (int*)(inv_in + N_NODES);       // NBUCK
    int*   gcurS   = gcurD + NBUCK;                  // NBUCK

    const int N = N_NODES;

    // K0: cursors
    init_kernel<<<1, 256, 0, stream>>>(gcurD, gcurS);

    // K1: edge placement (EXACT R4: 256 blocks x 256 thr, bufD+bufS, LDS cursors)
    place_kernel<<<NCHUNK, 256, 0, stream>>>(src, dst, gcurD, gcurS, bufD, bufS);

    // K2: dst-bucket sort ∥ src-bucket count + fused dense-1 -> csr/offs/inv_in/inv_out/hw
    bucket_dense_kernel<<<2 * NBUCK, NPB, 0, stream>>>(
        bufD, bufS, gcurD, gcurS, csr_src, offs, inv_in, inv_out,
        features, W, hw, N);

    // K3: fused layer-1 gather + layer-2 dense -> hw2
    gather_dense_kernel<<<GBLK, 256, 0, stream>>>(
        (const uint4*)hw, inv_in, inv_out, offs, csr_src, b, W, hw2, N);

    // K4: final gather -> out
    gather_kernel<<<GBLK, 256, 0, stream>>>(
        (const uint4*)hw2, inv_in, offs, csr_src, b, out, N);
}

// Round 9
// 231.237 us; speedup vs baseline: 3.0194x; 3.0194x over previous
//
#include <hip/hip_runtime.h>
#include <hip/hip_fp16.h>

#define N_NODES 100000
#define N_EDGES 1600000
#define HDIM 64
#define NPB 512                                  // nodes per bucket (pow2)
#define NPB_SHIFT 9
#define NBUCK 196                                // ceil(100000/512)
#define CAP 16384                                // per-bucket slot capacity
#define NCHUNK 256                               // place blocks (R4-measured config)
#define CHUNK (N_EDGES / NCHUNK)                 // 6250 edges/block
#define GBLK 3125                                // gather blocks (32 rows, N = 3125*32)

typedef float f4v __attribute__((ext_vector_type(4)));

// ---------------- K0: init global bucket cursors ----------------
__global__ void init_kernel(int* __restrict__ gcurD, int* __restrict__ gcurS) {
    int t = threadIdx.x;
    if (t < NBUCK) {
        gcurD[t] = t * CAP;
        gcurS[t] = t * CAP;
    }
}

__device__ inline uint2 f4_to_h4(float x, float y, float z, float w) {
    __half2 lo = __floats2half2_rn(x, y);
    __half2 hi = __floats2half2_rn(z, w);
    uint2 r;
    r.x = *(unsigned*)&lo;
    r.y = *(unsigned*)&hi;
    return r;
}

// ---------------- K1: place edges into fixed-capacity bucket regions (EXACT R4) ----------------
__global__ void place_kernel(const int* __restrict__ src, const int* __restrict__ dst,
                             int* __restrict__ gcurD, int* __restrict__ gcurS,
                             unsigned int* __restrict__ bufD, unsigned short* __restrict__ bufS) {
    __shared__ int hD[NBUCK], hS[NBUCK], curD[NBUCK], curS[NBUCK];
    int t = threadIdx.x, blk = blockIdx.x;
    for (int i = t; i < NBUCK; i += 256) { hD[i] = 0; hS[i] = 0; }
    __syncthreads();
    int e0 = blk * CHUNK;
    // pass 1: count (chunk ~50 KB -> L1/L2 hot for pass 2)
    for (int i = t; i < CHUNK; i += 256) {
        atomicAdd(&hD[dst[e0 + i] >> NPB_SHIFT], 1);
        atomicAdd(&hS[src[e0 + i] >> NPB_SHIFT], 1);
    }
    __syncthreads();
    // reserve runs
    for (int i = t; i < NBUCK; i += 256) {
        curD[i] = hD[i] ? atomicAdd(&gcurD[i], hD[i]) : 0;
        curS[i] = hS[i] ? atomicAdd(&gcurS[i], hS[i]) : 0;
    }
    __syncthreads();
    // pass 2: scatter
    for (int i = t; i < CHUNK; i += 256) {
        int s = src[e0 + i], d = dst[e0 + i];
        int pd = atomicAdd(&curD[d >> NPB_SHIFT], 1);
        bufD[pd] = (unsigned)s | ((unsigned)(d & (NPB - 1)) << 17);
        int ps = atomicAdd(&curS[s >> NPB_SHIFT], 1);
        bufS[ps] = (unsigned short)(s & (NPB - 1));
    }
}

// ---------------- K2: merged per-bucket fine stage (R4 + wave-shfl scan) ----------------
// blocks [0,196): dst buckets -> counting sort to csr_src, offs(int2), inv_in
// blocks [196,392): src buckets -> counts -> inv_out
// ONLY change vs R4: the 512-wide Hillis-Steele scan (18 barriers) is replaced by the
// R7/R8-verified wave-shfl scan (6 shfl_up steps + 8-wave LDS combine, 2 barriers).
__global__ void bucket_kernel(const unsigned int* __restrict__ bufD,
                              const unsigned short* __restrict__ bufS,
                              const int* __restrict__ gcurD, const int* __restrict__ gcurS,
                              int* __restrict__ csr_src, int2* __restrict__ offs,
                              float* __restrict__ inv_in, float* __restrict__ inv_out) {
    __shared__ int cnt[NPB], cur[NPB];
    __shared__ int wsum[8];
    int t = threadIdx.x;   // blockDim = 512
    int blk = blockIdx.x;
    if (blk < NBUCK) {
        int b = blk;
        int ebase = b * CAP;
        int ecnt  = gcurD[b] - ebase;
        cnt[t] = 0;
        __syncthreads();
        for (int i = t; i < ecnt; i += NPB)
            atomicAdd(&cnt[(int)(bufD[ebase + i] >> 17)], 1);
        __syncthreads();
        int v = cnt[t];
        // wave-level inclusive scan (64 lanes, no barriers) + 8-wave combine
        int lane = t & 63, w = t >> 6;
        int p = v;
#pragma unroll
        for (int d = 1; d < 64; d <<= 1) {
            int x = __shfl_up(p, d, 64);
            if (lane >= d) p += x;
        }
        if (lane == 63) wsum[w] = p;
        __syncthreads();
        int base = 0;
#pragma unroll
        for (int i = 0; i < 8; ++i) base += (i < w) ? wsum[i] : 0;
        int excl = base + p - v;
        cur[t] = excl;
        int node = b * NPB + t;
        if (node < N_NODES) {
            offs[node] = make_int2(ebase + excl, ebase + excl + v);
            inv_in[node] = rsqrtf((float)max(v, 1));
        }
        __syncthreads();
        for (int i = t; i < ecnt; i += NPB) {
            unsigned en = bufD[ebase + i];
            int pos = atomicAdd(&cur[(int)(en >> 17)], 1);
            csr_src[ebase + pos] = (int)(en & 0x1FFFFu);
        }
    } else {
        int b = blk - NBUCK;
        int ebase = b * CAP;
        int ecnt  = gcurS[b] - ebase;
        cnt[t] = 0;
        __syncthreads();
        for (int i = t; i < ecnt; i += NPB)
            atomicAdd(&cnt[(int)bufS[ebase + i]], 1);
        __syncthreads();
        int node = b * NPB + t;
        if (node < N_NODES) inv_out[node] = rsqrtf((float)max(cnt[t], 1));
    }
}

// ---------------- K3: dense (EXACT R4): hw(fp16) = (h * inv_out[:,None]) @ W ----------------
__global__ void dense_kernel(const float* __restrict__ h, const float* __restrict__ inv_out,
                             const float* __restrict__ W, uint2* __restrict__ hw, int n) {
    __shared__ float Wlds[HDIM * HDIM];     // 16 KB
    __shared__ float Alds[32][HDIM + 1];    // 8.1 KB
    int t = threadIdx.x;
    int r0 = blockIdx.x * 32;

    for (int i = t; i < HDIM * HDIM / 4; i += 256)
        ((f4v*)Wlds)[i] = ((const f4v*)W)[i];

    for (int i = t; i < 512; i += 256) {    // 32 rows x 16 float4
        int r = i >> 4;
        int c4 = i & 15;
        int row = r0 + r;
        f4v v = {0.f, 0.f, 0.f, 0.f};
        float s = 0.f;
        if (row < n) {
            v = __builtin_nontemporal_load((const f4v*)h + (long long)row * 16 + c4);
            s = inv_out[row];
        }
        Alds[r][c4 * 4 + 0] = v.x * s;
        Alds[r][c4 * 4 + 1] = v.y * s;
        Alds[r][c4 * 4 + 2] = v.z * s;
        Alds[r][c4 * 4 + 3] = v.w * s;
    }
    __syncthreads();

    int tx = t & 15;        // col quad
    int ty = t >> 4;        // 16 row-pairs
    float4 acc0 = make_float4(0.f, 0.f, 0.f, 0.f);
    float4 acc1 = acc0;

#pragma unroll 8
    for (int k = 0; k < HDIM; ++k) {
        f4v w = ((const f4v*)(Wlds + k * HDIM))[tx];
        float a0 = Alds[2 * ty + 0][k];
        float a1 = Alds[2 * ty + 1][k];
        acc0.x = fmaf(a0, w.x, acc0.x); acc0.y = fmaf(a0, w.y, acc0.y);
        acc0.z = fmaf(a0, w.z, acc0.z); acc0.w = fmaf(a0, w.w, acc0.w);
        acc1.x = fmaf(a1, w.x, acc1.x); acc1.y = fmaf(a1, w.y, acc1.y);
        acc1.z = fmaf(a1, w.z, acc1.z); acc1.w = fmaf(a1, w.w, acc1.w);
    }

    int rb = r0 + 2 * ty;
    if (rb + 0 < n) hw[(long long)(rb + 0) * 16 + tx] = f4_to_h4(acc0.x, acc0.y, acc0.z, acc0.w);
    if (rb + 1 < n) hw[(long long)(rb + 1) * 16 + tx] = f4_to_h4(acc1.x, acc1.y, acc1.z, acc1.w);
}

// ---------------- K4: fused layer-1 gather + layer-2 dense (EXACT R4) ----------------
__global__ void gather_dense_kernel(const uint4* __restrict__ hw_in, const float* __restrict__ inv_in,
                                    const float* __restrict__ inv_out,
                                    const int2* __restrict__ offs, const int* __restrict__ csr_src,
                                    const float* __restrict__ bias, const float* __restrict__ W,
                                    uint2* __restrict__ hw_out, int n) {
    __shared__ float Wlds[HDIM * HDIM];     // 16 KB
    int t = threadIdx.x;
    for (int i = t; i < HDIM * HDIM / 4; i += 256)
        ((f4v*)Wlds)[i] = ((const f4v*)W)[i];

    int wave = t >> 6, lane = t & 63;
    int g = lane >> 3, gl = lane & 7;          // group 0..7, lane-in-group 0..7
    int row = blockIdx.x * 32 + wave * 8 + g;  // N = 3125 * 32 exactly -> always valid

    float acc0 = 0.f, acc1 = 0.f, acc2 = 0.f, acc3 = 0.f;
    float acc4 = 0.f, acc5 = 0.f, acc6 = 0.f, acc7 = 0.f;

    int2 oe = offs[row];
    int start = oe.x, end = oe.y;
    int gbase = g << 3;

    int jb = start;
    int mm = end - jb; if (mm > 8) mm = 8;
    int sidx = (mm > 0 && gl < mm) ? csr_src[jb + gl] : 0;

    while (jb < end) {
        int jb2 = jb + 8;
        int mm2 = end - jb2; if (mm2 > 8) mm2 = 8;
        int sidx2 = (jb2 < end && gl < mm2) ? csr_src[jb2 + gl] : 0;

        if (mm == 8) {
#pragma unroll
            for (int j = 0; j < 8; ++j) {
                int s = __shfl(sidx, gbase + j, 64);
                uint4 u = hw_in[(long long)s * 8 + gl];
                float2 f0 = __half22float2(*(__half2*)&u.x);
                float2 f1 = __half22float2(*(__half2*)&u.y);
                float2 f2 = __half22float2(*(__half2*)&u.z);
                float2 f3 = __half22float2(*(__half2*)&u.w);
                acc0 += f0.x; acc1 += f0.y; acc2 += f1.x; acc3 += f1.y;
                acc4 += f2.x; acc5 += f2.y; acc6 += f3.x; acc7 += f3.y;
            }
        } else {
            for (int j = 0; j < mm; ++j) {
                int s = __shfl(sidx, gbase + j, 64);
                uint4 u = hw_in[(long long)s * 8 + gl];
                float2 f0 = __half22float2(*(__half2*)&u.x);
                float2 f1 = __half22float2(*(__half2*)&u.y);
                float2 f2 = __half22float2(*(__half2*)&u.z);
                float2 f3 = __half22float2(*(__half2*)&u.w);
                acc0 += f0.x; acc1 += f0.y; acc2 += f1.x; acc3 += f1.y;
                acc4 += f2.x; acc5 += f2.y; acc6 += f3.x; acc7 += f3.y;
            }
        }
        jb = jb2; mm = mm2; sidx = sidx2;
    }

    // finish layer 1 in registers: h1 = relu(acc*inv_in + bias), pre-scale by inv_out[row]
    float sc = inv_in[row];
    float so = inv_out[row];                   // per-ROW scalar (not per-edge)
    float4 b0 = ((const float4*)bias)[gl * 2 + 0];
    float4 b1 = ((const float4*)bias)[gl * 2 + 1];
    f4v h0, h1;
    h0.x = fmaxf(fmaf(acc0, sc, b0.x), 0.f) * so;
    h0.y = fmaxf(fmaf(acc1, sc, b0.y), 0.f) * so;
    h0.z = fmaxf(fmaf(acc2, sc, b0.z), 0.f) * so;
    h0.w = fmaxf(fmaf(acc3, sc, b0.w), 0.f) * so;
    h1.x = fmaxf(fmaf(acc4, sc, b1.x), 0.f) * so;
    h1.y = fmaxf(fmaf(acc5, sc, b1.y), 0.f) * so;
    h1.z = fmaxf(fmaf(acc6, sc, b1.z), 0.f) * so;
    h1.w = fmaxf(fmaf(acc7, sc, b1.w), 0.f) * so;

    __syncthreads();   // Wlds ready (all lanes reach here: no early returns)

    // layer-2 dense: hw_out[row] = (so*h1row) @ W
    float d0 = 0.f, d1 = 0.f, d2 = 0.f, d3 = 0.f;
    float d4 = 0.f, d5 = 0.f, d6 = 0.f, d7 = 0.f;
#pragma unroll
    for (int k = 0; k < HDIM; ++k) {
        float av = ((k >> 2) & 1) ? h1[k & 3] : h0[k & 3];   // static component
        float ak = __shfl(av, gbase + (k >> 3), 64);
        f4v w0 = ((const f4v*)Wlds)[k * 16 + gl * 2 + 0];
        f4v w1 = ((const f4v*)Wlds)[k * 16 + gl * 2 + 1];
        d0 = fmaf(ak, w0.x, d0); d1 = fmaf(ak, w0.y, d1);
        d2 = fmaf(ak, w0.z, d2); d3 = fmaf(ak, w0.w, d3);
        d4 = fmaf(ak, w1.x, d4); d5 = fmaf(ak, w1.y, d5);
        d6 = fmaf(ak, w1.z, d6); d7 = fmaf(ak, w1.w, d7);
    }

    hw_out[(long long)row * 16 + gl * 2 + 0] = f4_to_h4(d0, d1, d2, d3);
    hw_out[(long long)row * 16 + gl * 2 + 1] = f4_to_h4(d4, d5, d6, d7);
}

// ---------------- K5: final gather (EXACT R4): out = relu(inv_in*sum + b) ----------------
__global__ void gather_kernel(const uint4* __restrict__ hw, const float* __restrict__ inv_in,
                              const int2* __restrict__ offs, const int* __restrict__ csr_src,
                              const float* __restrict__ bias, float* __restrict__ out, int n) {
    int t = threadIdx.x;
    int wave = t >> 6, lane = t & 63;
    int g = lane >> 3, gl = lane & 7;
    int row = blockIdx.x * 32 + wave * 8 + g;
    if (row >= n) return;

    float acc0 = 0.f, acc1 = 0.f, acc2 = 0.f, acc3 = 0.f;
    float acc4 = 0.f, acc5 = 0.f, acc6 = 0.f, acc7 = 0.f;

    int2 oe = offs[row];
    int jb = oe.x, end = oe.y;
    int gbase = g << 3;

    int mm = end - jb; if (mm > 8) mm = 8;
    int sidx = (mm > 0 && gl < mm) ? csr_src[jb + gl] : 0;

    while (jb < end) {
        int jb2 = jb + 8;
        int mm2 = end - jb2; if (mm2 > 8) mm2 = 8;
        int sidx2 = (jb2 < end && gl < mm2) ? csr_src[jb2 + gl] : 0;

        if (mm == 8) {
#pragma unroll
            for (int j = 0; j < 8; ++j) {
                int s = __shfl(sidx, gbase + j, 64);
                uint4 u = hw[(long long)s * 8 + gl];
                float2 f0 = __half22float2(*(__half2*)&u.x);
                float2 f1 = __half22float2(*(__half2*)&u.y);
                float2 f2 = __half22float2(*(__half2*)&u.z);
                float2 f3 = __half22float2(*(__half2*)&u.w);
                acc0 += f0.x; acc1 += f0.y; acc2 += f1.x; acc3 += f1.y;
                acc4 += f2.x; acc5 += f2.y; acc6 += f3.x; acc7 += f3.y;
            }
        } else {
            for (int j = 0; j < mm; ++j) {
                int s = __shfl(sidx, gbase + j, 64);
                uint4 u = hw[(long long)s * 8 + gl];
                float2 f0 = __half22float2(*(__half2*)&u.x);
                float2 f1 = __half22float2(*(__half2*)&u.y);
                float2 f2 = __half22float2(*(__half2*)&u.z);
                float2 f3 = __half22float2(*(__half2*)&u.w);
                acc0 += f0.x; acc1 += f0.y; acc2 += f1.x; acc3 += f1.y;
                acc4 += f2.x; acc5 += f2.y; acc6 += f3.x; acc7 += f3.y;
            }
        }
        jb = jb2; mm = mm2; sidx = sidx2;
    }

    float sc = inv_in[row];
    float4 b0 = ((const float4*)bias)[gl * 2 + 0];
    float4 b1 = ((const float4*)bias)[gl * 2 + 1];
    f4v r0, r1;
    r0.x = fmaxf(fmaf(acc0, sc, b0.x), 0.f);
    r0.y = fmaxf(fmaf(acc1, sc, b0.y), 0.f);
    r0.z = fmaxf(fmaf(acc2, sc, b0.z), 0.f);
    r0.w = fmaxf(fmaf(acc3, sc, b0.w), 0.f);
    r1.x = fmaxf(fmaf(acc4, sc, b1.x), 0.f);
    r1.y = fmaxf(fmaf(acc5, sc, b1.y), 0.f);
    r1.z = fmaxf(fmaf(acc6, sc, b1.z), 0.f);
    r1.w = fmaxf(fmaf(acc7, sc, b1.w), 0.f);
    __builtin_nontemporal_store(r0, (f4v*)out + (long long)row * 16 + gl * 2 + 0);
    __builtin_nontemporal_store(r1, (f4v*)out + (long long)row * 16 + gl * 2 + 1);
}

extern "C" void kernel_launch(void* const* d_in, const int* in_sizes, int n_in,
                              void* d_out, int out_size, void* d_ws, size_t ws_size,
                              hipStream_t stream) {
    const float* features = (const float*)d_in[0];   // [N, 64]
    const float* W        = (const float*)d_in[1];   // [64, 64]
    const float* b        = (const float*)d_in[2];   // [64]
    const int*   src      = (const int*)d_in[3];     // [E]
    const int*   dst      = (const int*)d_in[4];     // [E]

    float* out = (float*)d_out;                      // [N, 64]

    // workspace layout (4-byte words); ~59 MB of 256 MB ws (same as R4)
    float* ws = (float*)d_ws;
    uint2* hw  = (uint2*)ws;                                            // N*32 words
    uint2* hw2 = (uint2*)(ws + (size_t)N_NODES * 32);                   // N*32 words
    unsigned int*   bufD = (unsigned int*)(ws + (size_t)N_NODES * 64);  // NBUCK*CAP words
    unsigned short* bufS = (unsigned short*)(bufD + (size_t)NBUCK * CAP); // NBUCK*CAP u16
    int*   csr_src = (int*)(bufS + (size_t)NBUCK * CAP);                // NBUCK*CAP words
    int2*  offs    = (int2*)(csr_src + (size_t)NBUCK * CAP);            // N int2
    float* inv_out = (float*)(offs + N_NODES);       // N
    float* inv_in  = inv_out + N_NODES;              // N
    int*   gcurD   = (int*)(inv_in + N_NODES);       // NBUCK
    int*   gcurS   = gcurD + NBUCK;                  // NBUCK

    const int N = N_NODES;

    // K0: cursors
    init_kernel<<<1, 256, 0, stream>>>(gcurD, gcurS);

    // K1: edge placement (EXACT R4)
    place_kernel<<<NCHUNK, 256, 0, stream>>>(src, dst, gcurD, gcurS, bufD, bufS);

    // K2: per-bucket fine stage (R4 + wave-shfl scan)
    bucket_kernel<<<2 * NBUCK, NPB, 0, stream>>>(bufD, bufS, gcurD, gcurS,
                                                 csr_src, offs, inv_in, inv_out);

    // K3: dense layer-1 -> hw
    dense_kernel<<<GBLK, 256, 0, stream>>>(features, inv_out, W, hw, N);

    // K4: fused layer-1 gather + layer-2 dense -> hw2
    gather_dense_kernel<<<GBLK, 256, 0, stream>>>(
        (const uint4*)hw, inv_in, inv_out, offs, csr_src, b, W, hw2, N);

    // K5: final gather -> out
    gather_kernel<<<GBLK, 256, 0, stream>>>(
        (const uint4*)hw2, inv_in, offs, csr_src, b, out, N);
}